// Round 1
// baseline (158.284 us; speedup 1.0000x reference)
//
#include <hip/hip_runtime.h>
#include <math.h>

#define BS 64
#define MUX_IN 8192
#define MUX_OUT 128
#define EPSF 1e-20f

// Map fp32 to monotonically-increasing unsigned key
__device__ __forceinline__ unsigned int sortable_f32(float f) {
    unsigned int b = __float_as_uint(f);
    return (b & 0x80000000u) ? ~b : (b | 0x80000000u);
}

// One block per batch row. 256 threads, 32 values/thread in registers.
// 128 rounds of block-wide argmax; winner's owning thread kills its value
// and rescans locally (static indices only; no runtime reg-array indexing).
__global__ __launch_bounds__(256) void topk_kernel(
        const float* __restrict__ logits,
        const float* __restrict__ u,
        int* __restrict__ topk) {
    const int b = blockIdx.x;
    const int t = threadIdx.x;
    const float* __restrict__ urow = u + (size_t)b * MUX_IN;

    float vals[32];
#pragma unroll
    for (int k = 0; k < 32; ++k) {
        const int i = k * 256 + t;           // coalesced
        const float uu = urow[i];
        const float gn = -logf(-logf(uu + EPSF) + EPSF);
        vals[k] = logits[i] + gn;
    }

    // per-thread running local max (value + which slot)
    float lv = vals[0];
    int lk = 0;
#pragma unroll
    for (int k = 1; k < 32; ++k) {
        if (vals[k] > lv) { lv = vals[k]; lk = k; }
    }

    __shared__ unsigned long long wmax[4];
    __shared__ int winner;

    for (int j = 0; j < MUX_OUT; ++j) {
        const int li = lk * 256 + t;
        // pack: high 32 = sortable value, low 32 = (MUX_IN-1-index) so that
        // max-reduce prefers larger value, then LOWER index (top_k tie rule)
        unsigned long long key =
            ((unsigned long long)sortable_f32(lv) << 32) |
            (unsigned)(MUX_IN - 1 - li);

        // wave64 butterfly max
#pragma unroll
        for (int off = 32; off > 0; off >>= 1) {
            unsigned long long o = __shfl_xor(key, off, 64);
            if (o > key) key = o;
        }
        const int wave = t >> 6;
        if ((t & 63) == 0) wmax[wave] = key;
        __syncthreads();
        if (t == 0) {
            unsigned long long m = wmax[0];
#pragma unroll
            for (int w = 1; w < 4; ++w) if (wmax[w] > m) m = wmax[w];
            const int wi = MUX_IN - 1 - (int)(m & 0xFFFFFFFFu);
            winner = wi;
            topk[b * MUX_OUT + j] = wi;
        }
        __syncthreads();
        const int wi = winner;
        if ((wi & 255) == t) {
            // kill the winning slot with STATIC indexing, then rescan
            const int kw = wi >> 8;
#pragma unroll
            for (int k = 0; k < 32; ++k) if (k == kw) vals[k] = -INFINITY;
            lv = vals[0]; lk = 0;
#pragma unroll
            for (int k = 1; k < 32; ++k) {
                if (vals[k] > lv) { lv = vals[k]; lk = k; }
            }
        }
    }
}

// One block per output row (b*128 + j). Writes 8192 floats: zeros + one 1.0f.
__global__ __launch_bounds__(256) void scatter_kernel(
        const int* __restrict__ topk,
        float* __restrict__ out) {
    const int row = blockIdx.x;          // 0 .. BS*MUX_OUT-1
    const int t = threadIdx.x;
    const int idx = topk[row];
    float4* __restrict__ op = (float4*)(out + (size_t)row * MUX_IN);
    const int target = idx >> 2;
    const int lane4 = idx & 3;
#pragma unroll
    for (int k = 0; k < 8; ++k) {
        const int p = k * 256 + t;       // coalesced float4 stores
        float4 v = make_float4(0.f, 0.f, 0.f, 0.f);
        if (p == target) {
            if (lane4 == 0) v.x = 1.0f;
            else if (lane4 == 1) v.y = 1.0f;
            else if (lane4 == 2) v.z = 1.0f;
            else v.w = 1.0f;
        }
        op[p] = v;
    }
}

extern "C" void kernel_launch(void* const* d_in, const int* in_sizes, int n_in,
                              void* d_out, int out_size, void* d_ws, size_t ws_size,
                              hipStream_t stream) {
    const float* logits = (const float*)d_in[0];   // (1, 8192)
    // d_in[1] = inpData: unused by the reference's output
    const float* u = (const float*)d_in[2];        // (64, 1, 8192)
    int* topk = (int*)d_ws;                        // 64*128 ints = 32 KB
    float* out = (float*)d_out;                    // (64, 128, 8192) fp32

    topk_kernel<<<BS, 256, 0, stream>>>(logits, u, topk);
    scatter_kernel<<<BS * MUX_OUT, 256, 0, stream>>>(topk, out);
}

// Round 2
// 61.073 us; speedup vs baseline: 2.5917x; 2.5917x over previous
//
#include <hip/hip_runtime.h>
#include <math.h>

#define BS 64
#define MUX_IN 8192
#define MUX_OUT 128
#define EPSF 1e-20f

typedef unsigned int u32;
typedef unsigned long long u64;

// Map fp32 to monotonically-increasing unsigned key
__device__ __forceinline__ u32 sortable_f32(float f) {
    u32 b = __float_as_uint(f);
    return (b & 0x80000000u) ? ~b : (b | 0x80000000u);
}

// ---------------------------------------------------------------------------
// Kernel A: keys[b*8192 + i] = sortable(logits[i] + gumbel(u[b,i]))
// 512 blocks x 256 threads, 4 elements/thread, fully parallel.
// ---------------------------------------------------------------------------
__global__ __launch_bounds__(256) void keys_kernel(
        const float* __restrict__ logits,
        const float* __restrict__ u,
        u32* __restrict__ keys) {
    const int g = blockIdx.x * 256 + threadIdx.x;
    const int base = g * 4;                 // multiple of 4
    const int i = base & (MUX_IN - 1);      // within-row index (row-aligned)
    const float4 uu = *(const float4*)(u + base);
    const float4 lg = *(const float4*)(logits + i);
    uint4 kk;
    {
        float in0 = -logf(uu.x + EPSF) + EPSF; kk.x = sortable_f32(lg.x - logf(in0));
        float in1 = -logf(uu.y + EPSF) + EPSF; kk.y = sortable_f32(lg.y - logf(in1));
        float in2 = -logf(uu.z + EPSF) + EPSF; kk.z = sortable_f32(lg.z - logf(in2));
        float in3 = -logf(uu.w + EPSF) + EPSF; kk.w = sortable_f32(lg.w - logf(in3));
    }
    *(uint4*)(keys + base) = kk;
}

// ---------------------------------------------------------------------------
// Kernel B: per-row exact top-128 indices (descending, lowest-index tie-break)
// via 4x 8-bit radix select + compact + 256-entry bitonic sort.
// One block of 256 threads per row; 32 keys/thread in registers.
// ---------------------------------------------------------------------------
__global__ __launch_bounds__(256) void select_kernel(
        const u32* __restrict__ keys,
        int* __restrict__ topk) {
    const int b = blockIdx.x;
    const int t = threadIdx.x;
    const u32* __restrict__ krow = keys + (size_t)b * MUX_IN;

    u32 kv[32];
#pragma unroll
    for (int q = 0; q < 8; ++q) {
        const uint4 v = *(const uint4*)(krow + q * 1024 + t * 4);
        kv[q * 4 + 0] = v.x; kv[q * 4 + 1] = v.y;
        kv[q * 4 + 2] = v.z; kv[q * 4 + 3] = v.w;
    }
    // element index of kv[k] within the row: (k>>2)*1024 + t*4 + (k&3)

    __shared__ u32 hist[4][256];      // wave-private copies (less atomic serialization)
    __shared__ u32 suf[256];
    __shared__ int sK;
    __shared__ u32 sSel;
    __shared__ int cnt;
    __shared__ u64 list[256];

    if (t == 0) { sK = MUX_OUT; sSel = 0u; cnt = 0; }
    const int wv = t >> 6;

    for (int pass = 0; pass < 4; ++pass) {
        const int sh = 24 - pass * 8;
#pragma unroll
        for (int w = 0; w < 4; ++w) hist[w][t] = 0u;
        __syncthreads();

        const u32 mask = (pass == 0) ? 0u : (0xFFFFFFFFu << (sh + 8));
        const u32 sel = sSel;
        const int K = sK;
#pragma unroll
        for (int k = 0; k < 32; ++k) {
            if (((kv[k] ^ sel) & mask) == 0u)
                atomicAdd(&hist[wv][(kv[k] >> sh) & 255u], 1u);
        }
        __syncthreads();

        const u32 c = hist[0][t] + hist[1][t] + hist[2][t] + hist[3][t];
        suf[t] = c;
        __syncthreads();
        // inclusive suffix sum over suf[0..255]
        for (int off = 1; off < 256; off <<= 1) {
            const u32 v = suf[t] + ((t + off < 256) ? suf[t + off] : 0u);
            __syncthreads();
            suf[t] = v;
            __syncthreads();
        }
        const u32 gt = (t < 255) ? suf[t + 1] : 0u;   // count of keys in bins > t
        if ((int)gt < K && (int)(gt + c) >= K) {       // exactly one thread
            sSel = sel | ((u32)t << sh);
            sK = K - (int)gt;
        }
        __syncthreads();
    }

    // T = sSel is the 128th-largest key value. Collect all keys >= T.
    const u32 T = sSel;
#pragma unroll
    for (int k = 0; k < 32; ++k) {
        if (kv[k] >= T) {
            const int slot = atomicAdd(&cnt, 1);
            if (slot < 256) {
                const int gi = (k >> 2) * 1024 + t * 4 + (k & 3);
                list[slot] = ((u64)kv[k] << 32) | (u32)(MUX_IN - 1 - gi);
            }
        }
    }
    __syncthreads();
    int c0 = cnt; if (c0 > 256) c0 = 256;
    for (int idx = c0 + t; idx < 256; idx += 256) list[idx] = 0ull;
    __syncthreads();

    // Bitonic sort 256 u64 entries, descending. Equal keys: larger inv-index
    // (= lower element index) first — matches top_k tie-break.
    for (int kk = 2; kk <= 256; kk <<= 1) {
        for (int j = kk >> 1; j > 0; j >>= 1) {
            const int ixj = t ^ j;
            if (ixj > t) {
                const u64 a = list[t];
                const u64 bb = list[ixj];
                const bool desc = ((t & kk) == 0);
                if (desc ? (a < bb) : (a > bb)) { list[t] = bb; list[ixj] = a; }
            }
            __syncthreads();
        }
    }

    if (t < MUX_OUT) {
        const u64 e = list[t];
        topk[b * MUX_OUT + t] = MUX_IN - 1 - (int)(e & 0xFFFFFFFFull);
    }
}

// ---------------------------------------------------------------------------
// Kernel C: one block per output row (b*128 + j); writes 8192 floats:
// zeros + a single 1.0f at the selected index.
// ---------------------------------------------------------------------------
__global__ __launch_bounds__(256) void scatter_kernel(
        const int* __restrict__ topk,
        float* __restrict__ out) {
    const int row = blockIdx.x;            // 0 .. BS*MUX_OUT-1
    const int t = threadIdx.x;
    const int idx = topk[row];
    float4* __restrict__ op = (float4*)(out + (size_t)row * MUX_IN);
    const int target = idx >> 2;
    const int lane4 = idx & 3;
#pragma unroll
    for (int k = 0; k < 8; ++k) {
        const int p = k * 256 + t;         // coalesced float4 stores
        float4 v = make_float4(0.f, 0.f, 0.f, 0.f);
        if (p == target) {
            if (lane4 == 0) v.x = 1.0f;
            else if (lane4 == 1) v.y = 1.0f;
            else if (lane4 == 2) v.z = 1.0f;
            else v.w = 1.0f;
        }
        op[p] = v;
    }
}

extern "C" void kernel_launch(void* const* d_in, const int* in_sizes, int n_in,
                              void* d_out, int out_size, void* d_ws, size_t ws_size,
                              hipStream_t stream) {
    const float* logits = (const float*)d_in[0];   // (1, 8192)
    // d_in[1] = inpData: not needed for the output
    const float* u = (const float*)d_in[2];        // (64, 1, 8192)
    float* out = (float*)d_out;                    // (64, 128, 8192) fp32

    // Scratch: keys live in the TAIL of d_out (2 MB); scatter fully
    // overwrites d_out afterwards, so this leaves no stale state.
    u32* keys = (u32*)(out + ((size_t)out_size - (size_t)BS * MUX_IN));
    int* topk = (int*)d_ws;                        // 64*128 ints = 32 KB

    keys_kernel<<<(BS * MUX_IN) / (256 * 4), 256, 0, stream>>>(logits, u, keys);
    select_kernel<<<BS, 256, 0, stream>>>(keys, topk);
    scatter_kernel<<<BS * MUX_OUT, 256, 0, stream>>>(topk, out);
}

// Round 3
// 42.481 us; speedup vs baseline: 3.7260x; 1.4377x over previous
//
#include <hip/hip_runtime.h>
#include <math.h>

#define BS 64
#define MUX_IN 8192
#define MUX_OUT 128
#define EPSF 1e-20f

#define NFILL_BLOCKS 1984
#define NBLOCKS (64 + NFILL_BLOCKS)
#define OUT_FLOAT4 ((size_t)BS * MUX_OUT * MUX_IN / 4)   // 16,777,216

typedef unsigned int u32;
typedef unsigned long long u64;

// Map fp32 to monotonically-increasing unsigned key
__device__ __forceinline__ u32 sortable_f32(float f) {
    u32 b = __float_as_uint(f);
    return (b & 0x80000000u) ? ~b : (b | 0x80000000u);
}

// ---------------------------------------------------------------------------
// Fused kernel:
//   blocks 0..63      : per-row keys (in-register) + radix-select + bitonic
//                       sort -> topk[b*128..] (exact jax.lax.top_k order)
//   blocks 64..2047   : grid-stride zero-fill of the whole 268 MB output
// No inter-block dependencies -> normal launch; select hides under fill.
// ---------------------------------------------------------------------------
__global__ __launch_bounds__(256) void fused_kernel(
        const float* __restrict__ logits,
        const float* __restrict__ u,
        int* __restrict__ topk,
        float* __restrict__ out) {
    const int t = threadIdx.x;

    if (blockIdx.x >= 64) {
        // ---------------- zero-fill path ----------------
        const size_t tid = (size_t)(blockIdx.x - 64) * 256 + t;
        const size_t nthreads = (size_t)NFILL_BLOCKS * 256;
        float4* __restrict__ o4 = (float4*)out;
        const float4 z = make_float4(0.f, 0.f, 0.f, 0.f);
        for (size_t p = tid; p < OUT_FLOAT4; p += nthreads) o4[p] = z;
        return;
    }

    // ---------------- select path (one block per batch row) ----------------
    const int b = blockIdx.x;
    const float* __restrict__ urow = u + (size_t)b * MUX_IN;

    // compute this row's 8192 sortable keys, 32 per thread, in registers
    u32 kv[32];
#pragma unroll
    for (int q = 0; q < 8; ++q) {
        const int base = q * 1024 + t * 4;
        const float4 uu = *(const float4*)(urow + base);
        const float4 lg = *(const float4*)(logits + base);
        float in0 = -logf(uu.x + EPSF) + EPSF; kv[q * 4 + 0] = sortable_f32(lg.x - logf(in0));
        float in1 = -logf(uu.y + EPSF) + EPSF; kv[q * 4 + 1] = sortable_f32(lg.y - logf(in1));
        float in2 = -logf(uu.z + EPSF) + EPSF; kv[q * 4 + 2] = sortable_f32(lg.z - logf(in2));
        float in3 = -logf(uu.w + EPSF) + EPSF; kv[q * 4 + 3] = sortable_f32(lg.w - logf(in3));
    }
    // element index of kv[k] within the row: (k>>2)*1024 + t*4 + (k&3)

    __shared__ u32 hist[4][256];      // wave-private copies
    __shared__ u32 suf[256];
    __shared__ int sK;
    __shared__ u32 sSel;
    __shared__ int cnt;
    __shared__ u64 list[256];

    if (t == 0) { sK = MUX_OUT; sSel = 0u; cnt = 0; }
    const int wv = t >> 6;

    // 4x 8-bit radix passes narrowing to the 128th-largest key value
    for (int pass = 0; pass < 4; ++pass) {
        const int sh = 24 - pass * 8;
#pragma unroll
        for (int w = 0; w < 4; ++w) hist[w][t] = 0u;
        __syncthreads();

        const u32 mask = (pass == 0) ? 0u : (0xFFFFFFFFu << (sh + 8));
        const u32 sel = sSel;
        const int K = sK;
#pragma unroll
        for (int k = 0; k < 32; ++k) {
            if (((kv[k] ^ sel) & mask) == 0u)
                atomicAdd(&hist[wv][(kv[k] >> sh) & 255u], 1u);
        }
        __syncthreads();

        const u32 c = hist[0][t] + hist[1][t] + hist[2][t] + hist[3][t];
        suf[t] = c;
        __syncthreads();
        // inclusive suffix sum over suf[0..255]
        for (int off = 1; off < 256; off <<= 1) {
            const u32 v = suf[t] + ((t + off < 256) ? suf[t + off] : 0u);
            __syncthreads();
            suf[t] = v;
            __syncthreads();
        }
        const u32 gt = (t < 255) ? suf[t + 1] : 0u;   // keys in bins > t
        if ((int)gt < K && (int)(gt + c) >= K) {       // exactly one thread
            sSel = sel | ((u32)t << sh);
            sK = K - (int)gt;
        }
        __syncthreads();
    }

    // T = 128th-largest key. Collect all keys >= T (always in [128, 256)
    // unless >128 exact duplicates of T, which random fp32 won't produce;
    // slots >=256 are dropped defensively).
    const u32 T = sSel;
#pragma unroll
    for (int k = 0; k < 32; ++k) {
        if (kv[k] >= T) {
            const int slot = atomicAdd(&cnt, 1);
            if (slot < 256) {
                const int gi = (k >> 2) * 1024 + t * 4 + (k & 3);
                list[slot] = ((u64)kv[k] << 32) | (u32)(MUX_IN - 1 - gi);
            }
        }
    }
    __syncthreads();
    int c0 = cnt; if (c0 > 256) c0 = 256;
    for (int idx = c0 + t; idx < 256; idx += 256) list[idx] = 0ull;
    __syncthreads();

    // Bitonic sort 256 u64 entries, descending; ties -> lower element index
    // first (matches jax.lax.top_k).
    for (int kk = 2; kk <= 256; kk <<= 1) {
        for (int j = kk >> 1; j > 0; j >>= 1) {
            const int ixj = t ^ j;
            if (ixj > t) {
                const u64 a = list[t];
                const u64 bb = list[ixj];
                const bool desc = ((t & kk) == 0);
                if (desc ? (a < bb) : (a > bb)) { list[t] = bb; list[ixj] = a; }
            }
            __syncthreads();
        }
    }

    if (t < MUX_OUT) {
        const u64 e = list[t];
        topk[b * MUX_OUT + t] = MUX_IN - 1 - (int)(e & 0xFFFFFFFFull);
    }
}

// ---------------------------------------------------------------------------
// Ones kernel: 8192 scattered 1.0f stores. Separate launch => kernel-boundary
// coherence orders these after the zero-fill (no cross-XCD WAW hazard).
// ---------------------------------------------------------------------------
__global__ __launch_bounds__(256) void ones_kernel(
        const int* __restrict__ topk,
        float* __restrict__ out) {
    const int r = blockIdx.x * 256 + threadIdx.x;   // output row 0..8191
    out[(size_t)r * MUX_IN + topk[r]] = 1.0f;
}

extern "C" void kernel_launch(void* const* d_in, const int* in_sizes, int n_in,
                              void* d_out, int out_size, void* d_ws, size_t ws_size,
                              hipStream_t stream) {
    const float* logits = (const float*)d_in[0];   // (1, 8192)
    // d_in[1] = inpData: not needed for the output
    const float* u = (const float*)d_in[2];        // (64, 1, 8192)
    float* out = (float*)d_out;                    // (64, 128, 8192) fp32
    int* topk = (int*)d_ws;                        // 64*128 ints = 32 KB

    fused_kernel<<<NBLOCKS, 256, 0, stream>>>(logits, u, topk, out);
    ones_kernel<<<(BS * MUX_OUT) / 256, 256, 0, stream>>>(topk, out);
}